// Round 9
// baseline (812.552 us; speedup 1.0000x reference)
//
#include <hip/hip_runtime.h>
#include <hip/hip_bf16.h>

#define H64 64

typedef __bf16 bf16_t;
typedef __bf16 bf16x8 __attribute__((ext_vector_type(8)));
typedef float f32x4 __attribute__((ext_vector_type(4)));

// ---------- helpers ----------
__device__ __forceinline__ float wload(const void* p, long i, bool f32) {
    return f32 ? ((const float*)p)[i]
               : __bfloat162float(((const __hip_bfloat16*)p)[i]);
}
__device__ __forceinline__ float blo(unsigned v) { return __uint_as_float(v << 16); }
__device__ __forceinline__ float bhi(unsigned v) { return __uint_as_float(v & 0xffff0000u); }
__device__ __forceinline__ unsigned packbf(float lo, float hi) {
    __hip_bfloat162 t;
    t.x = __float2bfloat16(lo);
    t.y = __float2bfloat16(hi);
    return *(unsigned*)&t;
}
__device__ __forceinline__ void acc8(float* s, uint4 v, unsigned m) {
    s[0] += blo(v.x & m); s[1] += bhi(v.x & m);
    s[2] += blo(v.y & m); s[3] += bhi(v.y & m);
    s[4] += blo(v.z & m); s[5] += bhi(v.z & m);
    s[6] += blo(v.w & m); s[7] += bhi(v.w & m);
}

// ---------- runtime format detection ----------
// flags[0] != 0 -> edge indices int32 (odd words nonzero); ==0 -> int64
// flags[1] > 64 -> x tensors f32; else bf16.  flags[2] > 64 -> weights f32.
__global__ void detect_k(const unsigned int* __restrict__ eiw, int nwords,
                         const unsigned short* __restrict__ xw,
                         const unsigned short* __restrict__ ww,
                         unsigned int* __restrict__ flags) {
    int t = threadIdx.x;
    unsigned int acc = 0;
    for (int i = 1 + 2 * t; i < nwords; i += 512) acc |= eiw[i];
    if (acc) atomicOr(&flags[0], acc);
    unsigned int cx = 0, cw = 0;
    for (int i = t; i < 8192; i += 256) {
        unsigned short w = xw[i];
        unsigned int e = (w >> 7) & 0xFF;
        if ((w & 0x7FFF) && (e == 0xFF || e < 0x40)) cx++;
        w = ww[i];
        e = (w >> 7) & 0xFF;
        if ((w & 0x7FFF) && (e == 0xFF || e < 0x40)) cw++;
    }
    if (cx) atomicAdd(&flags[1], cx);
    if (cw) atomicAdd(&flags[2], cw);
}

// ---------- convert all x inputs -> bf16 ws storage (uint4-vectorized) ----------
// one uint4 (8 bf16) per thread; block-uniform type resolution via block ranges.
struct ConvArgs {
    const void* src[4];
    long ubase[4];    // dst offset per type, in uint4 units
    long units[4];    // uint4 units per type
    int blkBase[5];   // cumulative block ranges per type
};
__global__ void conv_in_all(ConvArgs ca, __hip_bfloat16* __restrict__ dst,
                            const unsigned int* __restrict__ flags) {
    bool xf32 = flags[1] > 64;
    int b = blockIdx.x;
    int t = 0;
    while (t < 3 && b >= ca.blkBase[t + 1]) ++t;
    long lu = (long)(b - ca.blkBase[t]) * 256 + threadIdx.x;
    if (lu >= ca.units[t]) return;
    uint4* d4 = (uint4*)dst + ca.ubase[t] + lu;
    if (xf32) {
        const uint4* s = (const uint4*)ca.src[t] + 2 * lu;
        uint4 a = s[0], c = s[1];
        uint4 o;
        o.x = packbf(__uint_as_float(a.x), __uint_as_float(a.y));
        o.y = packbf(__uint_as_float(a.z), __uint_as_float(a.w));
        o.z = packbf(__uint_as_float(c.x), __uint_as_float(c.y));
        o.w = packbf(__uint_as_float(c.z), __uint_as_float(c.w));
        *d4 = o;
    } else {
        *d4 = ((const uint4*)ca.src[t])[lu];
    }
}

// ---------- weight prep: bf16, transposed WT[n][k]; Wr pre-summed per (l,dt) ----------
// blockIdx.x = l*13 + p.  p<9: WT of Wl[l,p].  p in 9..12: dt=p-9, WT of sum(Wr) + blsum.
__global__ void prep_w(const void* __restrict__ Wl, const void* __restrict__ Wr,
                       const void* __restrict__ bl, const unsigned int* __restrict__ flags,
                       bf16_t* __restrict__ wt, float* __restrict__ blsum) {
    const int rel_dt[9] = {0, 1, 2, 1, 2, 2, 3, 3, 3};
    bool wf32 = flags[2] > 64;
    int l = blockIdx.x / 13, p = blockIdx.x % 13;
    bf16_t* dst = wt + (long)blockIdx.x * 4096;
    for (int i = threadIdx.x; i < 4096; i += 256) {
        int n = i >> 6, k = i & 63;
        float v;
        if (p < 9) {
            v = wload(Wl, (long)(l * 9 + p) * 4096 + k * 64 + n, wf32);
        } else {
            int dt = p - 9;
            v = 0.f;
            for (int r = 0; r < 9; ++r)
                if (rel_dt[r] == dt) v += wload(Wr, (long)(l * 9 + r) * 4096 + k * 64 + n, wf32);
        }
        __hip_bfloat16 h = __float2bfloat16(v);
        dst[i] = *(bf16_t*)&h;
    }
    if (p >= 9 && threadIdx.x < 64) {
        int dt = p - 9;
        float s = 0.f;
        for (int r = 0; r < 9; ++r)
            if (rel_dt[r] == dt) s += wload(bl, (long)(l * 9 + r) * 64 + threadIdx.x, wf32);
        blsum[(l * 4 + dt) * 64 + threadIdx.x] = s;
    }
}

// ---------- consolidated CSR build (2 edges per thread) ----------
struct EdgeArgs {
    const int* ei[9];
    long eoff[10];    // edge offsets, cumulative
    long e2off[10];   // 2-edge-unit offsets, cumulative
    int cntoff[9];
    int srcbase[9];
};

// count + emit per-edge rank
__global__ void count_all(EdgeArgs ea, const unsigned int* __restrict__ flags,
                          int* __restrict__ cnt, int* __restrict__ rank) {
    long u = (long)blockIdx.x * 256 + threadIdx.x;
    if (u >= ea.e2off[9]) return;
    int r = 0;
    while (r < 8 && u >= ea.e2off[r + 1]) ++r;
    long el2 = u - ea.e2off[r];
    long E = ea.eoff[r + 1] - ea.eoff[r];
    long e0 = 2 * el2;
    bool two = (e0 + 1 < E);
    bool is64 = (flags[0] == 0u);
    const int* ei = ea.ei[r];
    int d0, d1 = 0;
    if (is64) { d0 = ei[2 * E + 2 * e0]; if (two) d1 = ei[2 * E + 2 * e0 + 2]; }
    else      { d0 = ei[E + e0];         if (two) d1 = ei[E + e0 + 1]; }
    int base = ea.cntoff[r];
    long eg = ea.eoff[r] + e0;
    rank[eg] = atomicAdd(&cnt[base + d0], 1);
    if (two) rank[eg + 1] = atomicAdd(&cnt[base + d1], 1);
}

// atomic-free fill: pos = row_ptr[dst] + rank[e]
__global__ void fill_all(EdgeArgs ea, const unsigned int* __restrict__ flags,
                         const int* __restrict__ row_ptr, const int* __restrict__ rank,
                         int* __restrict__ edge_src) {
    long u = (long)blockIdx.x * 256 + threadIdx.x;
    if (u >= ea.e2off[9]) return;
    int r = 0;
    while (r < 8 && u >= ea.e2off[r + 1]) ++r;
    long el2 = u - ea.e2off[r];
    long E = ea.eoff[r + 1] - ea.eoff[r];
    long e0 = 2 * el2;
    bool two = (e0 + 1 < E);
    bool is64 = (flags[0] == 0u);
    const int* ei = ea.ei[r];
    int s0, d0, s1 = 0, d1 = 0;
    if (is64) {
        s0 = ei[2 * e0];     d0 = ei[2 * E + 2 * e0];
        if (two) { s1 = ei[2 * e0 + 2]; d1 = ei[2 * E + 2 * e0 + 2]; }
    } else {
        s0 = ei[e0];         d0 = ei[E + e0];
        if (two) { s1 = ei[e0 + 1]; d1 = ei[E + e0 + 1]; }
    }
    int base = ea.cntoff[r], sb = ea.srcbase[r];
    long eg = ea.eoff[r] + e0;
    edge_src[row_ptr[base + d0] + rank[eg]] = sb + s0;
    if (two) edge_src[row_ptr[base + d1] + rank[eg + 1]] = sb + s1;
}

__global__ void scan_bsum(const int* __restrict__ cnt, int n, int* __restrict__ bsums) {
    __shared__ int red[256];
    int i = blockIdx.x * 256 + threadIdx.x;
    red[threadIdx.x] = (i < n) ? cnt[i] : 0;
    __syncthreads();
    for (int s = 128; s; s >>= 1) {
        if (threadIdx.x < s) red[threadIdx.x] += red[threadIdx.x + s];
        __syncthreads();
    }
    if (threadIdx.x == 0) bsums[blockIdx.x] = red[0];
}

__global__ void scan_excl_single(int* __restrict__ data, int n) {
    __shared__ int buf[1024];
    __shared__ int carry_s;
    if (threadIdx.x == 0) carry_s = 0;
    __syncthreads();
    for (int base = 0; base < n; base += 1024) {
        int i = base + threadIdx.x;
        int v = (i < n) ? data[i] : 0;
        buf[threadIdx.x] = v;
        __syncthreads();
        for (int off = 1; off < 1024; off <<= 1) {
            int tv = (threadIdx.x >= off) ? buf[threadIdx.x - off] : 0;
            __syncthreads();
            buf[threadIdx.x] += tv;
            __syncthreads();
        }
        int incl = buf[threadIdx.x];
        int carry = carry_s;
        if (i < n) data[i] = carry + incl - v;
        __syncthreads();
        if (threadIdx.x == 1023) carry_s = carry + buf[1023];
        __syncthreads();
    }
}

__global__ void scan_rowptr(const int* __restrict__ cnt, const int* __restrict__ bsums,
                            int n, int* __restrict__ row_ptr) {
    __shared__ int buf[256];
    int i = blockIdx.x * 256 + threadIdx.x;
    int v = (i < n) ? cnt[i] : 0;
    buf[threadIdx.x] = v;
    __syncthreads();
    for (int off = 1; off < 256; off <<= 1) {
        int tv = (threadIdx.x >= off) ? buf[threadIdx.x - off] : 0;
        __syncthreads();
        buf[threadIdx.x] += tv;
        __syncthreads();
    }
    int excl = buf[threadIdx.x] - v + bsums[blockIdx.x];
    if (i < n) row_ptr[i] = excl;
    if (i == n - 1) row_ptr[n] = excl + v;
}

// ---------- fused layer v4: per-WAVE 16-row tiles, overlapped pass issue ----------
struct FusedArgs {
    int cntOff[4][3];
    int wtSlot[4][4];
    long dstBase[4];
    int nDst[4];
    int Rdt[4];
    int blsumOff[4];
    int btBase[5];   // in 16-row-tile units, heavy-first order
    int dtOf[4];
    int totalT16;
};

// in-flight gather state for one pass (first 4 edges)
struct GSt {
    int rp0, rp1;
    uint4 v0[4], v1[4];
};

__device__ __forceinline__ void issue_g(GSt& g, const uint4* __restrict__ xq,
        const int* __restrict__ edge_src, const int* __restrict__ row_ptr,
        int cr, bool valid, int gp) {
    g.rp0 = 0; g.rp1 = 0;
    if (valid) { g.rp0 = row_ptr[cr]; g.rp1 = row_ptr[cr + 1]; }
    int idx4[4];
    #pragma unroll
    for (int j = 0; j < 4; ++j) {
        int ee = g.rp0 + j;
        idx4[j] = edge_src[(ee < g.rp1) ? ee : 0];
    }
    #pragma unroll
    for (int j = 0; j < 4; ++j) {
        bool ok = (g.rp0 + j < g.rp1);
        unsigned ofs = (unsigned)idx4[j] * 8u + (unsigned)gp * 2u;
        g.v0[j] = xq[ok ? ofs : 0u];
        g.v1[j] = xq[ok ? ofs + 1u : 0u];
    }
}

__device__ __forceinline__ void finish_g(const GSt& g, unsigned* __restrict__ L,
        const uint4* __restrict__ xq, const int* __restrict__ edge_src,
        int gr, int gp) {
    float s[16];
    #pragma unroll
    for (int j = 0; j < 16; ++j) s[j] = 0.f;
    #pragma unroll
    for (int j = 0; j < 4; ++j) {
        unsigned m = (g.rp0 + j < g.rp1) ? 0xFFFFFFFFu : 0u;
        acc8(s, g.v0[j], m);
        acc8(s + 8, g.v1[j], m);
    }
    for (int e = g.rp0 + 4; e < g.rp1; e += 4) {   // leftover (deg>4 rows)
        int idx4[4];
        #pragma unroll
        for (int j = 0; j < 4; ++j) {
            int ee = e + j;
            idx4[j] = edge_src[(ee < g.rp1) ? ee : 0];
        }
        uint4 v0[4], v1[4];
        #pragma unroll
        for (int j = 0; j < 4; ++j) {
            bool ok = (e + j < g.rp1);
            unsigned ofs = (unsigned)idx4[j] * 8u + (unsigned)gp * 2u;
            v0[j] = xq[ok ? ofs : 0u];
            v1[j] = xq[ok ? ofs + 1u : 0u];
        }
        #pragma unroll
        for (int j = 0; j < 4; ++j) {
            unsigned m = (e + j < g.rp1) ? 0xFFFFFFFFu : 0u;
            acc8(s, v0[j], m);
            acc8(s + 8, v1[j], m);
        }
    }
    float inv = (g.rp1 > g.rp0) ? 1.0f / (float)(g.rp1 - g.rp0) : 0.f;
    unsigned base = (unsigned)gr * 32u;
    #pragma unroll
    for (int h = 0; h < 2; ++h) {
        int d = gp * 8 + h * 4;
        unsigned idxw = base + (unsigned)(d ^ ((gr & 7) << 2));
        uint4 o;
        o.x = packbf(s[h * 8 + 0] * inv, s[h * 8 + 1] * inv);
        o.y = packbf(s[h * 8 + 2] * inv, s[h * 8 + 3] * inv);
        o.z = packbf(s[h * 8 + 4] * inv, s[h * 8 + 5] * inv);
        o.w = packbf(s[h * 8 + 6] * inv, s[h * 8 + 7] * inv);
        *(uint4*)&L[idxw] = o;
    }
}

// serial full gather (used for the third pass, R==3)
__device__ __forceinline__ void gather_pass(
    unsigned* __restrict__ L,
    const uint4* __restrict__ xq,
    const int* __restrict__ edge_src,
    const int* __restrict__ row_ptr,
    int cr, bool valid, int gr, int gp) {
    GSt g;
    issue_g(g, xq, edge_src, row_ptr, cr, valid, gp);
    finish_g(g, L, xq, edge_src, gr, gp);
}

__device__ __forceinline__ void mfma_pass(f32x4* acc, const bf16_t* wb,
                                          bf16x8 a0, bf16x8 a1, int l16, int quad) {
    #pragma unroll
    for (int nt = 0; nt < 4; ++nt) {
        bf16x8 b0 = *(const bf16x8*)(wb + (nt * 16 + l16) * 64 + quad * 8);
        bf16x8 b1 = *(const bf16x8*)(wb + (nt * 16 + l16) * 64 + 32 + quad * 8);
        acc[nt] = __builtin_amdgcn_mfma_f32_16x16x32_bf16(a0, b0, acc[nt], 0, 0, 0);
        acc[nt] = __builtin_amdgcn_mfma_f32_16x16x32_bf16(a1, b1, acc[nt], 0, 0, 0);
    }
}

__global__ __launch_bounds__(256) void fused_layer(
    const __hip_bfloat16* __restrict__ xin,
    __hip_bfloat16* __restrict__ xout,
    const int* __restrict__ edge_src,
    const int* __restrict__ row_ptr,
    const bf16_t* __restrict__ wt,
    const float* __restrict__ blsum,
    FusedArgs fa) {
    __shared__ unsigned lds[4][2 * 512];   // per wave: 2 regions x 16 rows x 128B = 16KB/block

    int wv = threadIdx.x >> 6;
    int g = blockIdx.x * 4 + wv;
    if (g >= fa.totalT16) return;
    int slot = 0;
    while (slot < 3 && g >= fa.btBase[slot + 1]) ++slot;
    int dt = fa.dtOf[slot];
    int t0 = g - fa.btBase[slot];
    int nD = fa.nDst[dt];
    int R = fa.Rdt[dt];

    int lane = threadIdx.x & 63;
    int gr = lane >> 2, gp = lane & 3;     // gather: row 0..15, 32B part 0..3
    int row = t0 * 16 + gr;
    bool valid = (row < nD);
    int quad = lane >> 4, l16 = lane & 15; // MFMA roles

    const uint4* xq = (const uint4*)xin;
    unsigned* L = lds[wv];

    // self-pass A loads: issue early, consume at the end (in flight under gathers)
    const bf16_t* ab = (const bf16_t*)xin + (fa.dstBase[dt] + (long)t0 * 16) * 64;
    bf16x8 sa0 = *(const bf16x8*)(ab + l16 * 64 + quad * 8);
    bf16x8 sa1 = *(const bf16x8*)(ab + l16 * 64 + 32 + quad * 8);

    unsigned sw = (unsigned)((l16 & 7) << 2);
    unsigned o0 = (unsigned)l16 * 32u + ((unsigned)(quad * 4) ^ sw);
    unsigned o1 = (unsigned)l16 * 32u + ((unsigned)(16 + quad * 4) ^ sw);
    f32x4 acc[4] = {};

    // overlapped issue of p0 and p1 (rowptr/idx/row latency chains run concurrently)
    GSt gA, gB;
    issue_g(gA, xq, edge_src, row_ptr, fa.cntOff[dt][0] + row, valid, gp);
    if (R > 1)
        issue_g(gB, xq, edge_src, row_ptr, fa.cntOff[dt][1] + row, valid, gp);
    __builtin_amdgcn_sched_barrier(0);   // keep both issue chains above the finishes

    finish_g(gA, L, xq, edge_src, gr, gp);
    if (R > 1)
        finish_g(gB, L + 512, xq, edge_src, gr, gp);

    asm volatile("s_waitcnt lgkmcnt(0)" ::: "memory");
    __builtin_amdgcn_sched_barrier(0);

    // read A-fragments p0/p1, then drain reads so region0 can be safely reused
    bf16x8 a00 = *(const bf16x8*)&L[o0];
    bf16x8 a01 = *(const bf16x8*)&L[o1];
    bf16x8 a10 = a00, a11 = a01;
    if (R > 1) { a10 = *(const bf16x8*)&L[512 + o0]; a11 = *(const bf16x8*)&L[512 + o1]; }
    asm volatile("s_waitcnt lgkmcnt(0)" ::: "memory");
    __builtin_amdgcn_sched_barrier(0);

    mfma_pass(acc, wt + (long)fa.wtSlot[dt][0] * 4096, a00, a01, l16, quad);
    if (R > 1)
        mfma_pass(acc, wt + (long)fa.wtSlot[dt][1] * 4096, a10, a11, l16, quad);

    if (R > 2) {
        // reuse region0 (p0 reads drained above)
        gather_pass(L, xq, edge_src, row_ptr, fa.cntOff[dt][2] + row, valid, gr, gp);
        asm volatile("s_waitcnt lgkmcnt(0)" ::: "memory");
        __builtin_amdgcn_sched_barrier(0);
        bf16x8 a20 = *(const bf16x8*)&L[o0];
        bf16x8 a21 = *(const bf16x8*)&L[o1];
        mfma_pass(acc, wt + (long)fa.wtSlot[dt][2] * 4096, a20, a21, l16, quad);
    }

    // self pass (x buffers padded +64 rows for tail overreads)
    mfma_pass(acc, wt + (long)fa.wtSlot[dt][3] * 4096, sa0, sa1, l16, quad);

    const float* bs = blsum + fa.blsumOff[dt];
    #pragma unroll
    for (int nt = 0; nt < 4; ++nt) {
        int col = nt * 16 + l16;
        float bv = bs[col];
        #pragma unroll
        for (int reg = 0; reg < 4; ++reg) {
            long dd = (long)t0 * 16 + quad * 4 + reg;
            if (dd < nD)
                xout[(fa.dstBase[dt] + dd) * 64 + col] =
                    __float2bfloat16(fmaxf(acc[nt][reg] + bv, 0.f));
        }
    }
}

// ---------- head: softplus(x@projW+projb) @ outW + outb ----------
__global__ __launch_bounds__(256) void head_k(
    const __hip_bfloat16* __restrict__ xc,
    const void* __restrict__ projW, const void* __restrict__ projb,
    const void* __restrict__ outW, const void* __restrict__ outb,
    void* __restrict__ out, const unsigned int* __restrict__ flags, int n) {
    __shared__ float PW[64 * 64];
    __shared__ float PB[64], OW[64];
    __shared__ float ROW[4][64];
    bool wf32 = flags[2] > 64;
    bool of32 = flags[1] > 64;
    int t = threadIdx.x;
    for (int i = t; i < 4096; i += 256) PW[i] = wload(projW, i, wf32);
    if (t < 64) { PB[t] = wload(projb, t, wf32); OW[t] = wload(outW, t, wf32); }
    int wid = t >> 6, lane = t & 63;
    int d = blockIdx.x * 4 + wid;
    ROW[wid][lane] = (d < n) ? __bfloat162float(xc[(long)d * H64 + lane]) : 0.f;
    __syncthreads();
    if (d < n) {
        float s = PB[lane];
        #pragma unroll 8
        for (int k = 0; k < 64; ++k) s += ROW[wid][k] * PW[k * 64 + lane];
        float sp = fmaxf(s, 0.f) + log1pf(expf(-fabsf(s)));
        float c = sp * OW[lane];
        #pragma unroll
        for (int off = 32; off; off >>= 1) c += __shfl_down(c, off, 64);
        if (lane == 0) {
            float rv = c + wload(outb, 0, wf32);
            if (of32) ((float*)out)[d] = rv;
            else ((__hip_bfloat16*)out)[d] = __float2bfloat16(rv);
        }
    }
}

extern "C" void kernel_launch(void* const* d_in, const int* in_sizes, int n_in,
                              void* d_out, int out_size, void* d_ws, size_t ws_size,
                              hipStream_t stream) {
    static const int rel_st[9] = {0, 0, 0, 1, 1, 2, 0, 1, 2};
    static const int rel_dt[9] = {0, 1, 2, 1, 2, 2, 3, 3, 3};
    static const int relsOf[4][3] = {{0, -1, -1}, {1, 3, -1}, {2, 4, 5}, {6, 7, 8}};
    static const int Rof[4] = {1, 2, 3, 3};
    static const int order[4] = {3, 0, 2, 1};   // heavy tiles first (cell, atom, motif, bond)

    long rows[4], rowoff[4], total = 0;
    for (int t = 0; t < 4; ++t) { rows[t] = in_sizes[t] / H64; rowoff[t] = total; total += rows[t]; }
    long NX = total * H64;
    long NXpad = (total + 64) * H64;           // +64 rows: tail-tile overread safety
    long Es[9], ET = 0;
    for (int r = 0; r < 9; ++r) { Es[r] = (long)in_sizes[11 + r] / 2; ET += Es[r]; }
    long cntoff[9], cntN = 0;
    for (int r = 0; r < 9; ++r) { cntoff[r] = cntN; cntN += rows[rel_dt[r]]; }
    long nb1 = (cntN + 255) / 256;

    unsigned int* flags = (unsigned int*)d_ws;
    char* wsbase = (char*)d_ws + 64;
    auto align16 = [](size_t v) { return (v + 15) & ~(size_t)15; };
    size_t off = 0;
    __hip_bfloat16* x0 = (__hip_bfloat16*)(wsbase + off);  off = align16(off + (size_t)NXpad * 2);
    __hip_bfloat16* x1 = (__hip_bfloat16*)(wsbase + off);  off = align16(off + (size_t)NXpad * 2);
    int* cnt_i = (int*)(wsbase + off);                     off = align16(off + (size_t)cntN * 4);
    int* row_ptr = (int*)(wsbase + off);                   off = align16(off + (size_t)(cntN + 1) * 4);
    int* rank = (int*)(wsbase + off);                      off = align16(off + (size_t)ET * 4);
    int* edge_src = (int*)(wsbase + off);                  off = align16(off + (size_t)ET * 4);
    int* bsums = (int*)(wsbase + off);                     off = align16(off + (size_t)nb1 * 4);
    bf16_t* wt = (bf16_t*)(wsbase + off);                  off = align16(off + (size_t)39 * 4096 * 2);
    float* blsum = (float*)(wsbase + off);                 off = align16(off + (size_t)12 * 64 * 4);

    // format detection
    hipMemsetAsync(d_ws, 0, 64, stream);
    int nwords = 16384;
    if (in_sizes[11] < nwords) nwords = in_sizes[11];
    detect_k<<<1, 256, 0, stream>>>((const unsigned int*)d_in[11], nwords,
                                    (const unsigned short*)d_in[0],
                                    (const unsigned short*)d_in[4], flags);

    // x inputs -> bf16 ws (uint4-vectorized, block-ranged by type)
    ConvArgs ca;
    int cb = 0;
    for (int t = 0; t < 4; ++t) {
        ca.src[t] = d_in[t];
        ca.ubase[t] = rowoff[t] * 8;          // 64 elem/row = 8 uint4
        ca.units[t] = rows[t] * 8;
        ca.blkBase[t] = cb;
        cb += (int)((ca.units[t] + 255) / 256);
    }
    ca.blkBase[4] = cb;
    conv_in_all<<<cb, 256, 0, stream>>>(ca, x0, flags);

    // weight prep (transpose + pre-sum, bf16)
    prep_w<<<39, 256, 0, stream>>>(d_in[4], d_in[6], d_in[5], flags, wt, blsum);

    // CSR build (edge structure is layer-invariant), 2 edges per thread
    EdgeArgs ea;
    long ecum = 0, e2cum = 0;
    for (int r = 0; r < 9; ++r) {
        ea.ei[r] = (const int*)d_in[11 + r];
        ea.eoff[r] = ecum;   ecum += Es[r];
        ea.e2off[r] = e2cum; e2cum += (Es[r] + 1) / 2;
        ea.cntoff[r] = (int)cntoff[r];
        ea.srcbase[r] = (int)rowoff[rel_st[r]];
    }
    ea.eoff[9] = ecum;
    ea.e2off[9] = e2cum;

    hipMemsetAsync(cnt_i, 0, (size_t)cntN * 4, stream);
    count_all<<<(int)((e2cum + 255) / 256), 256, 0, stream>>>(ea, flags, cnt_i, rank);
    scan_bsum<<<(int)nb1, 256, 0, stream>>>(cnt_i, (int)cntN, bsums);
    scan_excl_single<<<1, 1024, 0, stream>>>(bsums, (int)nb1);
    scan_rowptr<<<(int)nb1, 256, 0, stream>>>(cnt_i, bsums, (int)cntN, row_ptr);
    fill_all<<<(int)((e2cum + 255) / 256), 256, 0, stream>>>(ea, flags, row_ptr, rank, edge_src);

    // fused-layer argument block (layer-invariant parts), 16-row tiles
    FusedArgs fa;
    int bb = 0;
    for (int s = 0; s < 4; ++s) {
        int dt = order[s];
        fa.dtOf[s] = dt;
        fa.btBase[s] = bb;
        bb += (int)((rows[dt] + 15) / 16);
    }
    fa.btBase[4] = bb;
    fa.totalT16 = bb;
    for (int dt = 0; dt < 4; ++dt) {
        fa.nDst[dt] = (int)rows[dt];
        fa.Rdt[dt] = Rof[dt];
        fa.dstBase[dt] = rowoff[dt];
        for (int p = 0; p < 3; ++p) {
            int rr = (p < Rof[dt]) ? relsOf[dt][p] : relsOf[dt][0];
            fa.cntOff[dt][p] = (int)cntoff[rr];
        }
    }

    // layers: fused gather+update, ping-pong x
    for (int l = 0; l < 3; ++l) {
        for (int dt = 0; dt < 4; ++dt) {
            fa.blsumOff[dt] = (l * 4 + dt) * 64;
            for (int p = 0; p < 3; ++p) {
                int rr = (p < Rof[dt]) ? relsOf[dt][p] : relsOf[dt][0];
                fa.wtSlot[dt][p] = l * 13 + rr;
            }
            fa.wtSlot[dt][3] = l * 13 + 9 + dt;
        }
        const __hip_bfloat16* xin = (l & 1) ? x1 : x0;
        __hip_bfloat16* xo = (l & 1) ? x0 : x1;
        fused_layer<<<(bb + 3) / 4, 256, 0, stream>>>(xin, xo, edge_src, row_ptr, wt, blsum, fa);
    }

    // 3 layers -> final state in x1
    head_k<<<(int)((rows[3] + 3) / 4), 256, 0, stream>>>(
        x1 + rowoff[3] * H64, d_in[7], d_in[8], d_in[9], d_in[10], d_out, flags, (int)rows[3]);
}

// Round 10
// 767.737 us; speedup vs baseline: 1.0584x; 1.0584x over previous
//
#include <hip/hip_runtime.h>
#include <hip/hip_bf16.h>

#define H64 64

typedef __bf16 bf16_t;
typedef __bf16 bf16x8 __attribute__((ext_vector_type(8)));
typedef float f32x4 __attribute__((ext_vector_type(4)));

// ---------- helpers ----------
__device__ __forceinline__ float wload(const void* p, long i, bool f32) {
    return f32 ? ((const float*)p)[i]
               : __bfloat162float(((const __hip_bfloat16*)p)[i]);
}
__device__ __forceinline__ float blo(unsigned v) { return __uint_as_float(v << 16); }
__device__ __forceinline__ float bhi(unsigned v) { return __uint_as_float(v & 0xffff0000u); }
__device__ __forceinline__ unsigned packbf(float lo, float hi) {
    __hip_bfloat162 t;
    t.x = __float2bfloat16(lo);
    t.y = __float2bfloat16(hi);
    return *(unsigned*)&t;
}
__device__ __forceinline__ void acc8(float* s, uint4 v, unsigned m) {
    s[0] += blo(v.x & m); s[1] += bhi(v.x & m);
    s[2] += blo(v.y & m); s[3] += bhi(v.y & m);
    s[4] += blo(v.z & m); s[5] += bhi(v.z & m);
    s[6] += blo(v.w & m); s[7] += bhi(v.w & m);
}

// ---------- detect (multi-block) + zero cnt ----------
// flags[0] != 0 -> edge indices int32; flags[1] > 64 -> x f32; flags[2] > 64 -> w f32.
__global__ void detect_zero(const unsigned int* __restrict__ eiw, int nwords,
                            const unsigned short* __restrict__ xw,
                            const unsigned short* __restrict__ ww,
                            unsigned int* __restrict__ flags,
                            int4* __restrict__ cntz, long cnt4) {
    long gid = (long)blockIdx.x * 256 + threadIdx.x;
    long gsz = (long)gridDim.x * 256;
    for (long i = gid; i < cnt4; i += gsz) cntz[i] = make_int4(0, 0, 0, 0);
    unsigned int acc = 0;
    for (long i = 1 + 2 * gid; i < nwords; i += 2 * gsz) acc |= eiw[i];
    if (acc) atomicOr(&flags[0], acc);
    unsigned int cx = 0, cw = 0;
    for (long i = gid; i < 8192; i += gsz) {
        unsigned short w = xw[i];
        unsigned int e = (w >> 7) & 0xFF;
        if ((w & 0x7FFF) && (e == 0xFF || e < 0x40)) cx++;
        w = ww[i];
        e = (w >> 7) & 0xFF;
        if ((w & 0x7FFF) && (e == 0xFF || e < 0x40)) cw++;
    }
    if (cx) atomicAdd(&flags[1], cx);
    if (cw) atomicAdd(&flags[2], cw);
}

// ---------- merged weight-prep (blocks 0..38) + x convert (blocks 39..) ----------
struct ConvArgs {
    const void* src[4];
    long ubase[4];    // dst offset per type, in uint4 units
    long units[4];    // uint4 units per type
    int blkBase[5];   // cumulative conv block ranges per type
};
__global__ void conv_prep(ConvArgs ca, __hip_bfloat16* __restrict__ dst,
                          const void* __restrict__ Wl, const void* __restrict__ Wr,
                          const void* __restrict__ bl,
                          const unsigned int* __restrict__ flags,
                          bf16_t* __restrict__ wt, float* __restrict__ blsum) {
    if (blockIdx.x < 39) {
        // ---- weight prep: transposed WT[n][k]; Wr pre-summed per (l,dt) ----
        const int rel_dt[9] = {0, 1, 2, 1, 2, 2, 3, 3, 3};
        bool wf32 = flags[2] > 64;
        int l = blockIdx.x / 13, p = blockIdx.x % 13;
        bf16_t* dw = wt + (long)blockIdx.x * 4096;
        for (int i = threadIdx.x; i < 4096; i += 256) {
            int n = i >> 6, k = i & 63;
            float v;
            if (p < 9) {
                v = wload(Wl, (long)(l * 9 + p) * 4096 + k * 64 + n, wf32);
            } else {
                int dt = p - 9;
                v = 0.f;
                for (int r = 0; r < 9; ++r)
                    if (rel_dt[r] == dt) v += wload(Wr, (long)(l * 9 + r) * 4096 + k * 64 + n, wf32);
            }
            __hip_bfloat16 h = __float2bfloat16(v);
            dw[i] = *(bf16_t*)&h;
        }
        if (p >= 9 && threadIdx.x < 64) {
            int dt = p - 9;
            float s = 0.f;
            for (int r = 0; r < 9; ++r)
                if (rel_dt[r] == dt) s += wload(bl, (long)(l * 9 + r) * 64 + threadIdx.x, wf32);
            blsum[(l * 4 + dt) * 64 + threadIdx.x] = s;
        }
        return;
    }
    // ---- x convert: one uint4 (8 bf16) per thread ----
    bool xf32 = flags[1] > 64;
    int b = blockIdx.x - 39;
    int t = 0;
    while (t < 3 && b >= ca.blkBase[t + 1]) ++t;
    long lu = (long)(b - ca.blkBase[t]) * 256 + threadIdx.x;
    if (lu >= ca.units[t]) return;
    uint4* d4 = (uint4*)dst + ca.ubase[t] + lu;
    if (xf32) {
        const uint4* s = (const uint4*)ca.src[t] + 2 * lu;
        uint4 a = s[0], c = s[1];
        uint4 o;
        o.x = packbf(__uint_as_float(a.x), __uint_as_float(a.y));
        o.y = packbf(__uint_as_float(a.z), __uint_as_float(a.w));
        o.z = packbf(__uint_as_float(c.x), __uint_as_float(c.y));
        o.w = packbf(__uint_as_float(c.z), __uint_as_float(c.w));
        *d4 = o;
    } else {
        *d4 = ((const uint4*)ca.src[t])[lu];
    }
}

// ---------- consolidated CSR build (2 edges per thread) ----------
struct EdgeArgs {
    const int* ei[9];
    long eoff[10];    // edge offsets, cumulative
    long e2off[10];   // 2-edge-unit offsets, cumulative
    int cntoff[9];
    int srcbase[9];
};

__global__ void count_all(EdgeArgs ea, const unsigned int* __restrict__ flags,
                          int* __restrict__ cnt, int* __restrict__ rank) {
    long u = (long)blockIdx.x * 256 + threadIdx.x;
    if (u >= ea.e2off[9]) return;
    int r = 0;
    while (r < 8 && u >= ea.e2off[r + 1]) ++r;
    long el2 = u - ea.e2off[r];
    long E = ea.eoff[r + 1] - ea.eoff[r];
    long e0 = 2 * el2;
    bool two = (e0 + 1 < E);
    bool is64 = (flags[0] == 0u);
    const int* ei = ea.ei[r];
    int d0, d1 = 0;
    if (is64) { d0 = ei[2 * E + 2 * e0]; if (two) d1 = ei[2 * E + 2 * e0 + 2]; }
    else      { d0 = ei[E + e0];         if (two) d1 = ei[E + e0 + 1]; }
    int base = ea.cntoff[r];
    long eg = ea.eoff[r] + e0;
    rank[eg] = atomicAdd(&cnt[base + d0], 1);
    if (two) rank[eg + 1] = atomicAdd(&cnt[base + d1], 1);
}

__global__ void fill_all(EdgeArgs ea, const unsigned int* __restrict__ flags,
                         const int* __restrict__ row_ptr, const int* __restrict__ rank,
                         int* __restrict__ edge_src) {
    long u = (long)blockIdx.x * 256 + threadIdx.x;
    if (u >= ea.e2off[9]) return;
    int r = 0;
    while (r < 8 && u >= ea.e2off[r + 1]) ++r;
    long el2 = u - ea.e2off[r];
    long E = ea.eoff[r + 1] - ea.eoff[r];
    long e0 = 2 * el2;
    bool two = (e0 + 1 < E);
    bool is64 = (flags[0] == 0u);
    const int* ei = ea.ei[r];
    int s0, d0, s1 = 0, d1 = 0;
    if (is64) {
        s0 = ei[2 * e0];     d0 = ei[2 * E + 2 * e0];
        if (two) { s1 = ei[2 * e0 + 2]; d1 = ei[2 * E + 2 * e0 + 2]; }
    } else {
        s0 = ei[e0];         d0 = ei[E + e0];
        if (two) { s1 = ei[e0 + 1]; d1 = ei[E + e0 + 1]; }
    }
    int base = ea.cntoff[r], sb = ea.srcbase[r];
    long eg = ea.eoff[r] + e0;
    edge_src[row_ptr[base + d0] + rank[eg]] = sb + s0;
    if (two) edge_src[row_ptr[base + d1] + rank[eg + 1]] = sb + s1;
}

__global__ void scan_bsum(const int* __restrict__ cnt, int n, int* __restrict__ bsums) {
    __shared__ int red[256];
    int i = blockIdx.x * 256 + threadIdx.x;
    red[threadIdx.x] = (i < n) ? cnt[i] : 0;
    __syncthreads();
    for (int s = 128; s; s >>= 1) {
        if (threadIdx.x < s) red[threadIdx.x] += red[threadIdx.x + s];
        __syncthreads();
    }
    if (threadIdx.x == 0) bsums[blockIdx.x] = red[0];
}

// each block redundantly sums bsums[0..b) (L2-hot, <=nb ints), then scans its 256.
__global__ void scan_rowptr2(const int* __restrict__ cnt, const int* __restrict__ bsums,
                             int n, int* __restrict__ row_ptr) {
    __shared__ int red[256];
    __shared__ int buf[256];
    int b = blockIdx.x;
    int pre = 0;
    for (int i = threadIdx.x; i < b; i += 256) pre += bsums[i];
    red[threadIdx.x] = pre;
    __syncthreads();
    for (int s = 128; s; s >>= 1) {
        if (threadIdx.x < s) red[threadIdx.x] += red[threadIdx.x + s];
        __syncthreads();
    }
    int base = red[0];
    int i = b * 256 + threadIdx.x;
    int v = (i < n) ? cnt[i] : 0;
    buf[threadIdx.x] = v;
    __syncthreads();
    for (int off = 1; off < 256; off <<= 1) {
        int tv = (threadIdx.x >= off) ? buf[threadIdx.x - off] : 0;
        __syncthreads();
        buf[threadIdx.x] += tv;
        __syncthreads();
    }
    int excl = buf[threadIdx.x] - v + base;
    if (i < n) row_ptr[i] = excl;
    if (i == n - 1) row_ptr[n] = excl + v;
}

// ---------- fused layer (R8 v3): per-WAVE 16-row tiles, 2 LDS regions, barrier-free ----------
struct FusedArgs {
    int cntOff[4][3];
    int wtSlot[4][4];
    long dstBase[4];
    int nDst[4];
    int Rdt[4];
    int blsumOff[4];
    int btBase[5];   // in 16-row-tile units, heavy-first order
    int dtOf[4];
    int totalT16;
};

__device__ __forceinline__ void gather_pass(
    unsigned* __restrict__ L,          // this pass's 16x32-dword region
    const uint4* __restrict__ xq,
    const int* __restrict__ edge_src,
    const int* __restrict__ row_ptr,
    int cr, bool valid, int gr, int gp) {
    int rp0 = 0, rp1 = 0;
    if (valid) { rp0 = row_ptr[cr]; rp1 = row_ptr[cr + 1]; }
    float s[16];
    #pragma unroll
    for (int j = 0; j < 16; ++j) s[j] = 0.f;
    {   // static first-4-edges pipeline
        int idx4[4];
        #pragma unroll
        for (int j = 0; j < 4; ++j) {
            int ee = rp0 + j;
            idx4[j] = edge_src[(ee < rp1) ? ee : 0];
        }
        uint4 v0[4], v1[4];
        #pragma unroll
        for (int j = 0; j < 4; ++j) {
            bool ok = (rp0 + j < rp1);
            unsigned ofs = (unsigned)idx4[j] * 8u + (unsigned)gp * 2u;
            v0[j] = xq[ok ? ofs : 0u];
            v1[j] = xq[ok ? ofs + 1u : 0u];
        }
        #pragma unroll
        for (int j = 0; j < 4; ++j) {
            unsigned m = (rp0 + j < rp1) ? 0xFFFFFFFFu : 0u;
            acc8(s, v0[j], m);
            acc8(s + 8, v1[j], m);
        }
    }
    for (int e = rp0 + 4; e < rp1; e += 4) {   // leftover (deg>4 rows)
        int idx4[4];
        #pragma unroll
        for (int j = 0; j < 4; ++j) {
            int ee = e + j;
            idx4[j] = edge_src[(ee < rp1) ? ee : 0];
        }
        uint4 v0[4], v1[4];
        #pragma unroll
        for (int j = 0; j < 4; ++j) {
            bool ok = (e + j < rp1);
            unsigned ofs = (unsigned)idx4[j] * 8u + (unsigned)gp * 2u;
            v0[j] = xq[ok ? ofs : 0u];
            v1[j] = xq[ok ? ofs + 1u : 0u];
        }
        #pragma unroll
        for (int j = 0; j < 4; ++j) {
            unsigned m = (e + j < rp1) ? 0xFFFFFFFFu : 0u;
            acc8(s, v0[j], m);
            acc8(s + 8, v1[j], m);
        }
    }
    float inv = (rp1 > rp0) ? 1.0f / (float)(rp1 - rp0) : 0.f;
    unsigned base = (unsigned)gr * 32u;
    #pragma unroll
    for (int h = 0; h < 2; ++h) {
        int d = gp * 8 + h * 4;
        unsigned idxw = base + (unsigned)(d ^ ((gr & 7) << 2));
        uint4 o;
        o.x = packbf(s[h * 8 + 0] * inv, s[h * 8 + 1] * inv);
        o.y = packbf(s[h * 8 + 2] * inv, s[h * 8 + 3] * inv);
        o.z = packbf(s[h * 8 + 4] * inv, s[h * 8 + 5] * inv);
        o.w = packbf(s[h * 8 + 6] * inv, s[h * 8 + 7] * inv);
        *(uint4*)&L[idxw] = o;
    }
}

__device__ __forceinline__ void mfma_pass(f32x4* acc, const bf16_t* wb,
                                          bf16x8 a0, bf16x8 a1, int l16, int quad) {
    #pragma unroll
    for (int nt = 0; nt < 4; ++nt) {
        bf16x8 b0 = *(const bf16x8*)(wb + (nt * 16 + l16) * 64 + quad * 8);
        bf16x8 b1 = *(const bf16x8*)(wb + (nt * 16 + l16) * 64 + 32 + quad * 8);
        acc[nt] = __builtin_amdgcn_mfma_f32_16x16x32_bf16(a0, b0, acc[nt], 0, 0, 0);
        acc[nt] = __builtin_amdgcn_mfma_f32_16x16x32_bf16(a1, b1, acc[nt], 0, 0, 0);
    }
}

__global__ __launch_bounds__(256) void fused_layer(
    const __hip_bfloat16* __restrict__ xin,
    __hip_bfloat16* __restrict__ xout,
    const int* __restrict__ edge_src,
    const int* __restrict__ row_ptr,
    const bf16_t* __restrict__ wt,
    const float* __restrict__ blsum,
    FusedArgs fa) {
    __shared__ unsigned lds[4][2 * 512];   // per wave: 2 regions x 16 rows x 128B = 16KB/block

    int wv = threadIdx.x >> 6;
    int g = blockIdx.x * 4 + wv;
    if (g >= fa.totalT16) return;
    int slot = 0;
    while (slot < 3 && g >= fa.btBase[slot + 1]) ++slot;
    int dt = fa.dtOf[slot];
    int t0 = g - fa.btBase[slot];
    int nD = fa.nDst[dt];
    int R = fa.Rdt[dt];

    int lane = threadIdx.x & 63;
    int gr = lane >> 2, gp = lane & 3;     // gather: row 0..15, 32B part 0..3
    int row = t0 * 16 + gr;
    bool valid = (row < nD);
    int quad = lane >> 4, l16 = lane & 15; // MFMA roles

    const uint4* xq = (const uint4*)xin;
    unsigned* L = lds[wv];

    // self-pass A loads: issue early, consume at the end (in flight under gathers)
    const bf16_t* ab = (const bf16_t*)xin + (fa.dstBase[dt] + (long)t0 * 16) * 64;
    bf16x8 sa0 = *(const bf16x8*)(ab + l16 * 64 + quad * 8);
    bf16x8 sa1 = *(const bf16x8*)(ab + l16 * 64 + 32 + quad * 8);

    unsigned sw = (unsigned)((l16 & 7) << 2);
    unsigned o0 = (unsigned)l16 * 32u + ((unsigned)(quad * 4) ^ sw);
    unsigned o1 = (unsigned)l16 * 32u + ((unsigned)(16 + quad * 4) ^ sw);
    f32x4 acc[4] = {};

    // G0 -> region0, G1 -> region1
    gather_pass(L, xq, edge_src, row_ptr, fa.cntOff[dt][0] + row, valid, gr, gp);
    if (R > 1)
        gather_pass(L + 512, xq, edge_src, row_ptr, fa.cntOff[dt][1] + row, valid, gr, gp);

    asm volatile("s_waitcnt lgkmcnt(0)" ::: "memory");
    __builtin_amdgcn_sched_barrier(0);

    // read A-fragments p0/p1, then drain reads so region0 can be safely reused
    bf16x8 a00 = *(const bf16x8*)&L[o0];
    bf16x8 a01 = *(const bf16x8*)&L[o1];
    bf16x8 a10 = a00, a11 = a01;
    if (R > 1) { a10 = *(const bf16x8*)&L[512 + o0]; a11 = *(const bf16x8*)&L[512 + o1]; }
    asm volatile("s_waitcnt lgkmcnt(0)" ::: "memory");
    __builtin_amdgcn_sched_barrier(0);

    mfma_pass(acc, wt + (long)fa.wtSlot[dt][0] * 4096, a00, a01, l16, quad);
    if (R > 1)
        mfma_pass(acc, wt + (long)fa.wtSlot[dt][1] * 4096, a10, a11, l16, quad);

    if (R > 2) {
        // reuse region0 (p0 reads drained above)
        gather_pass(L, xq, edge_src, row_ptr, fa.cntOff[dt][2] + row, valid, gr, gp);
        asm volatile("s_waitcnt lgkmcnt(0)" ::: "memory");
        __builtin_amdgcn_sched_barrier(0);
        bf16x8 a20 = *(const bf16x8*)&L[o0];
        bf16x8 a21 = *(const bf16x8*)&L[o1];
        mfma_pass(acc, wt + (long)fa.wtSlot[dt][2] * 4096, a20, a21, l16, quad);
    }

    // self pass (x buffers padded +64 rows for tail overreads)
    mfma_pass(acc, wt + (long)fa.wtSlot[dt][3] * 4096, sa0, sa1, l16, quad);

    const float* bs = blsum + fa.blsumOff[dt];
    #pragma unroll
    for (int nt = 0; nt < 4; ++nt) {
        int col = nt * 16 + l16;
        float bv = bs[col];
        #pragma unroll
        for (int reg = 0; reg < 4; ++reg) {
            long dd = (long)t0 * 16 + quad * 4 + reg;
            if (dd < nD)
                xout[(fa.dstBase[dt] + dd) * 64 + col] =
                    __float2bfloat16(fmaxf(acc[nt][reg] + bv, 0.f));
        }
    }
}

// ---------- head: softplus(x@projW+projb) @ outW + outb ----------
__global__ __launch_bounds__(256) void head_k(
    const __hip_bfloat16* __restrict__ xc,
    const void* __restrict__ projW, const void* __restrict__ projb,
    const void* __restrict__ outW, const void* __restrict__ outb,
    void* __restrict__ out, const unsigned int* __restrict__ flags, int n) {
    __shared__ float PW[64 * 64];
    __shared__ float PB[64], OW[64];
    __shared__ float ROW[4][64];
    bool wf32 = flags[2] > 64;
    bool of32 = flags[1] > 64;
    int t = threadIdx.x;
    for (int i = t; i < 4096; i += 256) PW[i] = wload(projW, i, wf32);
    if (t < 64) { PB[t] = wload(projb, t, wf32); OW[t] = wload(outW, t, wf32); }
    int wid = t >> 6, lane = t & 63;
    int d = blockIdx.x * 4 + wid;
    ROW[wid][lane] = (d < n) ? __bfloat162float(xc[(long)d * H64 + lane]) : 0.f;
    __syncthreads();
    if (d < n) {
        float s = PB[lane];
        #pragma unroll 8
        for (int k = 0; k < 64; ++k) s += ROW[wid][k] * PW[k * 64 + lane];
        float sp = fmaxf(s, 0.f) + log1pf(expf(-fabsf(s)));
        float c = sp * OW[lane];
        #pragma unroll
        for (int off = 32; off; off >>= 1) c += __shfl_down(c, off, 64);
        if (lane == 0) {
            float rv = c + wload(outb, 0, wf32);
            if (of32) ((float*)out)[d] = rv;
            else ((__hip_bfloat16*)out)[d] = __float2bfloat16(rv);
        }
    }
}

extern "C" void kernel_launch(void* const* d_in, const int* in_sizes, int n_in,
                              void* d_out, int out_size, void* d_ws, size_t ws_size,
                              hipStream_t stream) {
    static const int rel_st[9] = {0, 0, 0, 1, 1, 2, 0, 1, 2};
    static const int rel_dt[9] = {0, 1, 2, 1, 2, 2, 3, 3, 3};
    static const int relsOf[4][3] = {{0, -1, -1}, {1, 3, -1}, {2, 4, 5}, {6, 7, 8}};
    static const int Rof[4] = {1, 2, 3, 3};
    static const int order[4] = {3, 0, 2, 1};   // heavy tiles first (cell, atom, motif, bond)

    long rows[4], rowoff[4], total = 0;
    for (int t = 0; t < 4; ++t) { rows[t] = in_sizes[t] / H64; rowoff[t] = total; total += rows[t]; }
    long NX = total * H64;
    long NXpad = (total + 64) * H64;           // +64 rows: tail-tile overread safety
    long Es[9], ET = 0;
    for (int r = 0; r < 9; ++r) { Es[r] = (long)in_sizes[11 + r] / 2; ET += Es[r]; }
    long cntoff[9], cntN = 0;
    for (int r = 0; r < 9; ++r) { cntoff[r] = cntN; cntN += rows[rel_dt[r]]; }
    long nb1 = (cntN + 255) / 256;

    unsigned int* flags = (unsigned int*)d_ws;
    char* wsbase = (char*)d_ws + 64;
    auto align16 = [](size_t v) { return (v + 15) & ~(size_t)15; };
    size_t off = 0;
    __hip_bfloat16* x0 = (__hip_bfloat16*)(wsbase + off);  off = align16(off + (size_t)NXpad * 2);
    __hip_bfloat16* x1 = (__hip_bfloat16*)(wsbase + off);  off = align16(off + (size_t)NXpad * 2);
    int* cnt_i = (int*)(wsbase + off);                     off = align16(off + (size_t)(cntN + 4) * 4);
    int* row_ptr = (int*)(wsbase + off);                   off = align16(off + (size_t)(cntN + 1) * 4);
    int* rank = (int*)(wsbase + off);                      off = align16(off + (size_t)ET * 4);
    int* edge_src = (int*)(wsbase + off);                  off = align16(off + (size_t)ET * 4);
    int* bsums = (int*)(wsbase + off);                     off = align16(off + (size_t)nb1 * 4);
    bf16_t* wt = (bf16_t*)(wsbase + off);                  off = align16(off + (size_t)39 * 4096 * 2);
    float* blsum = (float*)(wsbase + off);                 off = align16(off + (size_t)12 * 64 * 4);

    // flags zero + format detection + cnt zero (one kernel, multi-block)
    hipMemsetAsync(d_ws, 0, 64, stream);
    int nwords = 16384;
    if (in_sizes[11] < nwords) nwords = in_sizes[11];
    detect_zero<<<256, 256, 0, stream>>>((const unsigned int*)d_in[11], nwords,
                                         (const unsigned short*)d_in[0],
                                         (const unsigned short*)d_in[4], flags,
                                         (int4*)cnt_i, (cntN + 3) / 4);

    // merged weight-prep + x convert
    ConvArgs ca;
    int cb = 0;
    for (int t = 0; t < 4; ++t) {
        ca.src[t] = d_in[t];
        ca.ubase[t] = rowoff[t] * 8;          // 64 elem/row = 8 uint4
        ca.units[t] = rows[t] * 8;
        ca.blkBase[t] = cb;
        cb += (int)((ca.units[t] + 255) / 256);
    }
    ca.blkBase[4] = cb;
    conv_prep<<<39 + cb, 256, 0, stream>>>(ca, x0, d_in[4], d_in[6], d_in[5],
                                           flags, wt, blsum);

    // CSR build (edge structure is layer-invariant), 2 edges per thread
    EdgeArgs ea;
    long ecum = 0, e2cum = 0;
    for (int r = 0; r < 9; ++r) {
        ea.ei[r] = (const int*)d_in[11 + r];
        ea.eoff[r] = ecum;   ecum += Es[r];
        ea.e2off[r] = e2cum; e2cum += (Es[r] + 1) / 2;
        ea.cntoff[r] = (int)cntoff[r];
        ea.srcbase[r] = (int)rowoff[rel_st[r]];
    }
    ea.eoff[9] = ecum;
    ea.e2off[9] = e2cum;

    count_all<<<(int)((e2cum + 255) / 256), 256, 0, stream>>>(ea, flags, cnt_i, rank);
    scan_bsum<<<(int)nb1, 256, 0, stream>>>(cnt_i, (int)cntN, bsums);
    scan_rowptr2<<<(int)nb1, 256, 0, stream>>>(cnt_i, bsums, (int)cntN, row_ptr);
    fill_all<<<(int)((e2cum + 255) / 256), 256, 0, stream>>>(ea, flags, row_ptr, rank, edge_src);

    // fused-layer argument block (layer-invariant parts), 16-row tiles
    FusedArgs fa;
    int bb = 0;
    for (int s = 0; s < 4; ++s) {
        int dt = order[s];
        fa.dtOf[s] = dt;
        fa.btBase[s] = bb;
        bb += (int)((rows[dt] + 15) / 16);
    }
    fa.btBase[4] = bb;
    fa.totalT16 = bb;
    for (int dt = 0; dt < 4; ++dt) {
        fa.nDst[dt] = (int)rows[dt];
        fa.Rdt[dt] = Rof[dt];
        fa.dstBase[dt] = rowoff[dt];
        for (int p = 0; p < 3; ++p) {
            int rr = (p < Rof[dt]) ? relsOf[dt][p] : relsOf[dt][0];
            fa.cntOff[dt][p] = (int)cntoff[rr];
        }
    }

    // layers: fused gather+update, ping-pong x
    for (int l = 0; l < 3; ++l) {
        for (int dt = 0; dt < 4; ++dt) {
            fa.blsumOff[dt] = (l * 4 + dt) * 64;
            for (int p = 0; p < 3; ++p) {
                int rr = (p < Rof[dt]) ? relsOf[dt][p] : relsOf[dt][0];
                fa.wtSlot[dt][p] = l * 13 + rr;
            }
            fa.wtSlot[dt][3] = l * 13 + 9 + dt;
        }
        const __hip_bfloat16* xin = (l & 1) ? x1 : x0;
        __hip_bfloat16* xo = (l & 1) ? x0 : x1;
        fused_layer<<<(bb + 3) / 4, 256, 0, stream>>>(xin, xo, edge_src, row_ptr, wt, blsum, fa);
    }

    // 3 layers -> final state in x1
    head_k<<<(int)((rows[3] + 3) / 4), 256, 0, stream>>>(
        x1 + rowoff[3] * H64, d_in[7], d_in[8], d_in[9], d_in[10], d_out, flags, (int)rows[3]);
}